// Round 4
// baseline (616.180 us; speedup 1.0000x reference)
//
#include <hip/hip_runtime.h>
#include <hip/hip_bf16.h>
#include <stdint.h>

#define D_MODEL 1024
#define NHEAD   16
#define DH      64

typedef __attribute__((ext_vector_type(8))) short bf16x8;
typedef __attribute__((ext_vector_type(4))) float f32x4;

__device__ __forceinline__ ushort f2bf(float f) {
    __hip_bfloat16 h = __float2bfloat16(f);
    return *reinterpret_cast<ushort*>(&h);
}

// Load 8 contiguous elements as bf16x8; fp32 source converts in-register.
__device__ __forceinline__ bf16x8 load8(const float* p) {
    const float4 a = *(const float4*)p;
    const float4 b = *(const float4*)(p + 4);
    bf16x8 r;
    r[0] = (short)f2bf(a.x); r[1] = (short)f2bf(a.y);
    r[2] = (short)f2bf(a.z); r[3] = (short)f2bf(a.w);
    r[4] = (short)f2bf(b.x); r[5] = (short)f2bf(b.y);
    r[6] = (short)f2bf(b.z); r[7] = (short)f2bf(b.w);
    return r;
}
__device__ __forceinline__ bf16x8 load8(const ushort* p) {
    return *(const bf16x8*)p;
}

__device__ __forceinline__ void storeC(float*  C, size_t i, float v) { C[i] = v; }
__device__ __forceinline__ void storeC(ushort* C, size_t i, float v) { C[i] = (short)f2bf(v); }

// C = X (MxK) @ W^T (W is NxK) + bias, C row-major (MxN). bf16 MFMA compute.
template<typename TX, typename TW, typename TOUT>
__device__ __forceinline__ void gemm_core(
    const TX* __restrict__ X,
    const TW* __restrict__ W,
    const float* __restrict__ Bias,
    TOUT* __restrict__ C,
    int M, int N, int K,
    short* As, short* Bs)
{
    const int tid  = threadIdx.x;
    const int w    = tid >> 6;
    const int lane = tid & 63;
    const int quad = lane >> 4;
    const int l15  = lane & 15;
    const int wr   = w >> 1, wc = w & 1;
    const int m0 = blockIdx.y * 128;
    const int n0 = blockIdx.x * 128;

    f32x4 acc[4][4] = {};

    for (int k0 = 0; k0 < K; k0 += 32) {
        __syncthreads();   // WAR on LDS tiles
        #pragma unroll
        for (int c = 0; c < 2; ++c) {
            int idx = c * 256 + tid;        // 0..511
            int row = idx >> 2;             // 0..127
            int col = (idx & 3) * 8;        // 0,8,16,24
            *(bf16x8*)&As[row * 32 + col] = load8(X + (size_t)(m0 + row) * K + k0 + col);
            *(bf16x8*)&Bs[row * 32 + col] = load8(W + (size_t)(n0 + row) * K + k0 + col);
        }
        __syncthreads();

        bf16x8 af[4], bfr[4];
        #pragma unroll
        for (int i = 0; i < 4; ++i)
            af[i] = *(const bf16x8*)&As[(wr * 64 + i * 16 + l15) * 32 + quad * 8];
        #pragma unroll
        for (int j = 0; j < 4; ++j)
            bfr[j] = *(const bf16x8*)&Bs[(wc * 64 + j * 16 + l15) * 32 + quad * 8];
        #pragma unroll
        for (int i = 0; i < 4; ++i)
            #pragma unroll
            for (int j = 0; j < 4; ++j)
                acc[i][j] = __builtin_amdgcn_mfma_f32_16x16x32_bf16(af[i], bfr[j], acc[i][j], 0, 0, 0);
    }

    float bias[4];
    #pragma unroll
    for (int j = 0; j < 4; ++j)
        bias[j] = Bias[n0 + wc * 64 + j * 16 + l15];

    #pragma unroll
    for (int i = 0; i < 4; ++i) {
        int row = m0 + wr * 64 + i * 16 + quad * 4;
        #pragma unroll
        for (int j = 0; j < 4; ++j) {
            int col = n0 + wc * 64 + j * 16 + l15;
            #pragma unroll
            for (int r = 0; r < 4; ++r)
                storeC(C, (size_t)(row + r) * N + col, acc[i][j][r] + bias[j]);
        }
    }
}

__global__ __launch_bounds__(256) void qkv_proj_kernel(
    const float* __restrict__ Qin, const float* __restrict__ Kin,
    const float* __restrict__ Vin,
    const float* __restrict__ Wq, const float* __restrict__ Bq,
    const float* __restrict__ Wk, const float* __restrict__ Bk,
    const float* __restrict__ Wv, const float* __restrict__ Bv,
    ushort* qo, ushort* ko, ushort* vo, int L)
{
    __shared__ short As[4096];
    __shared__ short Bs[4096];
    const int z = blockIdx.z;
    const float *X, *W, *B; ushort* C;
    if (z == 0)      { X = Qin; W = Wq; B = Bq; C = qo; }
    else if (z == 1) { X = Kin; W = Wk; B = Bk; C = ko; }
    else             { X = Vin; W = Wv; B = Bv; C = vo; }
    gemm_core<float, float, ushort>(X, W, B, C, L, D_MODEL, D_MODEL, As, Bs);
}

__global__ __launch_bounds__(256) void out_proj_kernel(
    const ushort* __restrict__ Xa, const float* __restrict__ Wo,
    const float* __restrict__ Bo, float* out, int L)
{
    __shared__ short As[4096];
    __shared__ short Bs[4096];
    gemm_core<ushort, float, float>(Xa, Wo, Bo, out, L, D_MODEL, D_MODEL, As, Bs);
}

// Flash attention. Block = (64 Q rows, head). Wave w owns q rows w*16..w*16+15.
// qw,kw,vw,ow all (L, D_MODEL) bf16 (as ushort).
__global__ __launch_bounds__(256) void attn_kernel(
    const ushort* __restrict__ Qw,
    const ushort* __restrict__ Kw,
    const ushort* __restrict__ Vw,
    ushort* __restrict__ Ow, int L)
{
    __shared__ short Ks[64 * 64];       // [key][dh]
    __shared__ short Vs[64 * 64];       // [dh][key]  (transposed at staging)
    __shared__ short Ps[4][16 * 64];    // per-wave P tile [qrow][key]

    const int tid  = threadIdx.x;
    const int w    = tid >> 6;
    const int lane = tid & 63;
    const int quad = lane >> 4;
    const int l15  = lane & 15;
    const int h    = blockIdx.y;
    const int q0   = blockIdx.x * 64;

    const ushort* qp = Qw + (size_t)(q0 + w * 16 + l15) * D_MODEL + h * DH + quad * 8;
    bf16x8 qf0 = *(const bf16x8*)qp;
    bf16x8 qf1 = *(const bf16x8*)(qp + 32);

    f32x4 o[4] = {};
    float mrow[4] = {-3e38f, -3e38f, -3e38f, -3e38f};
    float lrow[4] = {0.f, 0.f, 0.f, 0.f};
    const float csc = 0.125f * 1.44269504088896f;   // log2(e)/sqrt(Dh)

    for (int key0 = 0; key0 < L; key0 += 64) {
        __syncthreads();   // WAR on Ks/Vs
        #pragma unroll
        for (int c = 0; c < 2; ++c) {
            int idx = c * 256 + tid;          // 0..511
            int key = idx >> 3;               // 0..63
            int dh0 = (idx & 7) * 8;          // 0..56
            bf16x8 kv = *(const bf16x8*)(Kw + (size_t)(key0 + key) * D_MODEL + h * DH + dh0);
            *(bf16x8*)&Ks[key * 64 + dh0] = kv;
            bf16x8 vv = *(const bf16x8*)(Vw + (size_t)(key0 + key) * D_MODEL + h * DH + dh0);
            #pragma unroll
            for (int i = 0; i < 8; ++i)
                Vs[(dh0 + i) * 64 + key] = vv[i];
        }
        __syncthreads();

        // S = Q K^T (raw; scale folded into exp2 constant)
        f32x4 s[4];
        #pragma unroll
        for (int jt = 0; jt < 4; ++jt) {
            bf16x8 kf0 = *(const bf16x8*)&Ks[(jt * 16 + l15) * 64 + quad * 8];
            bf16x8 kf1 = *(const bf16x8*)&Ks[(jt * 16 + l15) * 64 + 32 + quad * 8];
            f32x4 z = {};
            z = __builtin_amdgcn_mfma_f32_16x16x32_bf16(qf0, kf0, z, 0, 0, 0);
            z = __builtin_amdgcn_mfma_f32_16x16x32_bf16(qf1, kf1, z, 0, 0, 0);
            s[jt] = z;
        }

        // online softmax (rows = quad*4 + r within wave's 16-row tile)
        float mnew[4], alpha[4], rs[4];
        #pragma unroll
        for (int r = 0; r < 4; ++r) {
            float mx = fmaxf(fmaxf(s[0][r], s[1][r]), fmaxf(s[2][r], s[3][r]));
            mx = fmaxf(mx, __shfl_xor(mx, 1));
            mx = fmaxf(mx, __shfl_xor(mx, 2));
            mx = fmaxf(mx, __shfl_xor(mx, 4));
            mx = fmaxf(mx, __shfl_xor(mx, 8));
            mnew[r]  = fmaxf(mrow[r], mx);
            alpha[r] = exp2f((mrow[r] - mnew[r]) * csc);
            mrow[r]  = mnew[r];
            rs[r]    = 0.f;
        }
        #pragma unroll
        for (int jt = 0; jt < 4; ++jt) {
            #pragma unroll
            for (int r = 0; r < 4; ++r) {
                float p = exp2f((s[jt][r] - mnew[r]) * csc);
                rs[r] += p;
                Ps[w][(quad * 4 + r) * 64 + jt * 16 + l15] = (short)f2bf(p);
            }
        }
        #pragma unroll
        for (int r = 0; r < 4; ++r) {
            float t = rs[r];
            t += __shfl_xor(t, 1);
            t += __shfl_xor(t, 2);
            t += __shfl_xor(t, 4);
            t += __shfl_xor(t, 8);
            lrow[r] = lrow[r] * alpha[r] + t;
            #pragma unroll
            for (int dt = 0; dt < 4; ++dt) o[dt][r] *= alpha[r];
        }
        __syncthreads();   // Ps visible for A-layout re-read

        // O += P @ V   (A = P [qrow][key], B-frag[n=dh][k=key] = Vs[dh][key])
        #pragma unroll
        for (int f = 0; f < 2; ++f) {
            bf16x8 pf = *(const bf16x8*)&Ps[w][l15 * 64 + f * 32 + quad * 8];
            #pragma unroll
            for (int dt = 0; dt < 4; ++dt) {
                bf16x8 vf = *(const bf16x8*)&Vs[(dt * 16 + l15) * 64 + f * 32 + quad * 8];
                o[dt] = __builtin_amdgcn_mfma_f32_16x16x32_bf16(pf, vf, o[dt], 0, 0, 0);
            }
        }
    }

    #pragma unroll
    for (int r = 0; r < 4; ++r) {
        int row = q0 + w * 16 + quad * 4 + r;
        float inv = 1.f / lrow[r];
        #pragma unroll
        for (int dt = 0; dt < 4; ++dt) {
            int col = h * DH + dt * 16 + l15;
            Ow[(size_t)row * D_MODEL + col] = (short)f2bf(o[dt][r] * inv);
        }
    }
}

extern "C" void kernel_launch(void* const* d_in, const int* in_sizes, int n_in,
                              void* d_out, int out_size, void* d_ws, size_t ws_size,
                              hipStream_t stream) {
    // Reference dtypes: ALL inputs float32; output float32.
    const float* Q   = (const float*)d_in[0];
    const float* K   = (const float*)d_in[1];
    const float* V   = (const float*)d_in[2];
    const float* w_q = (const float*)d_in[3];
    const float* b_q = (const float*)d_in[4];
    const float* w_k = (const float*)d_in[5];
    const float* b_k = (const float*)d_in[6];
    const float* w_v = (const float*)d_in[7];
    const float* b_v = (const float*)d_in[8];
    const float* w_o = (const float*)d_in[9];
    const float* b_o = (const float*)d_in[10];
    float* out = (float*)d_out;

    const int L = in_sizes[0] / D_MODEL;   // 4096
    const size_t mat = (size_t)L * D_MODEL;

    // bf16 intermediates: q,k,a in d_ws (24 MB); projected V borrows the
    // upper 8 MB of the 16 MB fp32 d_out (dead before out_proj overwrites;
    // stream-ordered, every byte of d_out rewritten each call).
    ushort* q_ws = (ushort*)d_ws;
    ushort* k_ws = q_ws + mat;
    ushort* a_ws = k_ws + mat;
    ushort* v_ws = (ushort*)d_out + mat;   // bytes [8MB,16MB) of d_out

    dim3 blk(256);
    dim3 gqkv(D_MODEL / 128, L / 128, 3);
    qkv_proj_kernel<<<gqkv, blk, 0, stream>>>(Q, K, V, w_q, b_q, w_k, b_k, w_v, b_v,
                                              q_ws, k_ws, v_ws, L);
    dim3 gattn(L / 64, NHEAD);
    attn_kernel<<<gattn, blk, 0, stream>>>(q_ws, k_ws, v_ws, a_ws, L);
    dim3 gout(D_MODEL / 128, L / 128);
    out_proj_kernel<<<gout, blk, 0, stream>>>(a_ws, w_o, b_o, out, L);
}

// Round 5
// 490.507 us; speedup vs baseline: 1.2562x; 1.2562x over previous
//
#include <hip/hip_runtime.h>
#include <hip/hip_bf16.h>
#include <stdint.h>

#define D_MODEL 1024
#define NHEAD   16
#define DH      64

typedef __attribute__((ext_vector_type(8))) short bf16x8;
typedef __attribute__((ext_vector_type(4))) float f32x4;

__device__ __forceinline__ ushort f2bf(float f) {
    __hip_bfloat16 h = __float2bfloat16(f);
    return *reinterpret_cast<ushort*>(&h);
}

// Load 8 contiguous elements as bf16x8; fp32 source converts in-register.
__device__ __forceinline__ bf16x8 load8(const float* p) {
    const float4 a = *(const float4*)p;
    const float4 b = *(const float4*)(p + 4);
    bf16x8 r;
    r[0] = (short)f2bf(a.x); r[1] = (short)f2bf(a.y);
    r[2] = (short)f2bf(a.z); r[3] = (short)f2bf(a.w);
    r[4] = (short)f2bf(b.x); r[5] = (short)f2bf(b.y);
    r[6] = (short)f2bf(b.z); r[7] = (short)f2bf(b.w);
    return r;
}
__device__ __forceinline__ bf16x8 load8(const ushort* p) {
    return *(const bf16x8*)p;
}

__device__ __forceinline__ void storeC(float*  C, size_t i, float v) { C[i] = v; }
__device__ __forceinline__ void storeC(ushort* C, size_t i, float v) { C[i] = (short)f2bf(v); }

// C = X (MxK) @ W^T (W is NxK) + bias, C row-major (MxN). bf16 MFMA compute.
template<typename TX, typename TW, typename TOUT>
__device__ __forceinline__ void gemm_core(
    const TX* __restrict__ X,
    const TW* __restrict__ W,
    const float* __restrict__ Bias,
    TOUT* __restrict__ C,
    int M, int N, int K,
    short* As, short* Bs)
{
    const int tid  = threadIdx.x;
    const int w    = tid >> 6;
    const int lane = tid & 63;
    const int quad = lane >> 4;
    const int l15  = lane & 15;
    const int wr   = w >> 1, wc = w & 1;
    const int m0 = blockIdx.y * 128;
    const int n0 = blockIdx.x * 128;

    f32x4 acc[4][4] = {};

    for (int k0 = 0; k0 < K; k0 += 32) {
        __syncthreads();   // WAR on LDS tiles
        #pragma unroll
        for (int c = 0; c < 2; ++c) {
            int idx = c * 256 + tid;        // 0..511
            int row = idx >> 2;             // 0..127
            int col = (idx & 3) * 8;        // 0,8,16,24
            *(bf16x8*)&As[row * 32 + col] = load8(X + (size_t)(m0 + row) * K + k0 + col);
            *(bf16x8*)&Bs[row * 32 + col] = load8(W + (size_t)(n0 + row) * K + k0 + col);
        }
        __syncthreads();

        bf16x8 af[4], bfr[4];
        #pragma unroll
        for (int i = 0; i < 4; ++i)
            af[i] = *(const bf16x8*)&As[(wr * 64 + i * 16 + l15) * 32 + quad * 8];
        #pragma unroll
        for (int j = 0; j < 4; ++j)
            bfr[j] = *(const bf16x8*)&Bs[(wc * 64 + j * 16 + l15) * 32 + quad * 8];
        #pragma unroll
        for (int i = 0; i < 4; ++i)
            #pragma unroll
            for (int j = 0; j < 4; ++j)
                acc[i][j] = __builtin_amdgcn_mfma_f32_16x16x32_bf16(af[i], bfr[j], acc[i][j], 0, 0, 0);
    }

    float bias[4];
    #pragma unroll
    for (int j = 0; j < 4; ++j)
        bias[j] = Bias[n0 + wc * 64 + j * 16 + l15];

    #pragma unroll
    for (int i = 0; i < 4; ++i) {
        int row = m0 + wr * 64 + i * 16 + quad * 4;
        #pragma unroll
        for (int j = 0; j < 4; ++j) {
            int col = n0 + wc * 64 + j * 16 + l15;
            #pragma unroll
            for (int r = 0; r < 4; ++r)
                storeC(C, (size_t)(row + r) * N + col, acc[i][j][r] + bias[j]);
        }
    }
}

__global__ __launch_bounds__(256) void qkv_proj_kernel(
    const float* __restrict__ Qin, const float* __restrict__ Kin,
    const float* __restrict__ Vin,
    const float* __restrict__ Wq, const float* __restrict__ Bq,
    const float* __restrict__ Wk, const float* __restrict__ Bk,
    const float* __restrict__ Wv, const float* __restrict__ Bv,
    ushort* qo, ushort* ko, ushort* vo, int L)
{
    __shared__ short As[4096];
    __shared__ short Bs[4096];
    const int z = blockIdx.z;
    const float *X, *W, *B; ushort* C;
    if (z == 0)      { X = Qin; W = Wq; B = Bq; C = qo; }
    else if (z == 1) { X = Kin; W = Wk; B = Bk; C = ko; }
    else             { X = Vin; W = Wv; B = Bv; C = vo; }
    gemm_core<float, float, ushort>(X, W, B, C, L, D_MODEL, D_MODEL, As, Bs);
}

__global__ __launch_bounds__(256) void out_proj_kernel(
    const ushort* __restrict__ Xa, const float* __restrict__ Wo,
    const float* __restrict__ Bo, float* out, int L)
{
    __shared__ short As[4096];
    __shared__ short Bs[4096];
    gemm_core<ushort, float, float>(Xa, Wo, Bo, out, L, D_MODEL, D_MODEL, As, Bs);
}

// Flash attention. Block = (128 Q rows, head), 512 threads (8 waves x 16 q-rows).
// qw,kw,vw,ow all (L, D_MODEL) bf16 (as ushort).
__global__ __launch_bounds__(512) void attn_kernel(
    const ushort* __restrict__ Qw,
    const ushort* __restrict__ Kw,
    const ushort* __restrict__ Vw,
    ushort* __restrict__ Ow, int L)
{
    __shared__ short Ks[64 * 64];       // [key][dh]
    __shared__ short Vs[64 * 64];       // [dh][key]  (transposed at staging, lane=key)
    __shared__ short Ps[8][16 * 64];    // per-wave P tile, XOR-swizzled columns

    const int tid  = threadIdx.x;
    const int w    = tid >> 6;          // 0..7
    const int lane = tid & 63;
    const int quad = lane >> 4;
    const int l15  = lane & 15;
    const int h    = blockIdx.y;
    const int q0   = blockIdx.x * 128;

    // Q A-fragments held in registers for the whole block
    const ushort* qp = Qw + (size_t)(q0 + w * 16 + l15) * D_MODEL + h * DH + quad * 8;
    bf16x8 qf0 = *(const bf16x8*)(qp);
    bf16x8 qf1 = *(const bf16x8*)(qp + 32);

    // staging coordinates
    const int kkey = tid >> 3;          // K: 8 lanes per row -> coalesced
    const int kdh  = (tid & 7) * 8;
    const int vkey = lane;              // V: lane = key -> conflict-free LDS scatter
    const int vdh  = w * 8;

    f32x4 o[4] = {};
    float mrow[4] = {-3e38f, -3e38f, -3e38f, -3e38f};
    float lrow[4] = {0.f, 0.f, 0.f, 0.f};
    const float csc = 0.125f * 1.44269504088896f;   // log2(e)/sqrt(Dh)

    for (int key0 = 0; key0 < L; key0 += 64) {
        __syncthreads();   // WAR on Ks/Vs
        *(bf16x8*)&Ks[kkey * 64 + kdh] =
            *(const bf16x8*)(Kw + (size_t)(key0 + kkey) * D_MODEL + h * DH + kdh);
        bf16x8 vv = *(const bf16x8*)(Vw + (size_t)(key0 + vkey) * D_MODEL + h * DH + vdh);
        #pragma unroll
        for (int i = 0; i < 8; ++i)
            Vs[(vdh + i) * 64 + vkey] = vv[i];   // lanes consecutive -> 2-way, free
        __syncthreads();

        // S = Q K^T (raw; scale folded into exp2 constant)
        f32x4 s[4];
        #pragma unroll
        for (int jt = 0; jt < 4; ++jt) {
            bf16x8 kf0 = *(const bf16x8*)&Ks[(jt * 16 + l15) * 64 + quad * 8];
            bf16x8 kf1 = *(const bf16x8*)&Ks[(jt * 16 + l15) * 64 + 32 + quad * 8];
            f32x4 z = {};
            z = __builtin_amdgcn_mfma_f32_16x16x32_bf16(qf0, kf0, z, 0, 0, 0);
            z = __builtin_amdgcn_mfma_f32_16x16x32_bf16(qf1, kf1, z, 0, 0, 0);
            s[jt] = z;
        }

        // online softmax (rows = quad*4 + r within wave's 16-row tile)
        float mnew[4], alpha[4], rs[4];
        #pragma unroll
        for (int r = 0; r < 4; ++r) {
            float mx = fmaxf(fmaxf(s[0][r], s[1][r]), fmaxf(s[2][r], s[3][r]));
            mx = fmaxf(mx, __shfl_xor(mx, 1));
            mx = fmaxf(mx, __shfl_xor(mx, 2));
            mx = fmaxf(mx, __shfl_xor(mx, 4));
            mx = fmaxf(mx, __shfl_xor(mx, 8));
            mnew[r]  = fmaxf(mrow[r], mx);
            alpha[r] = __builtin_amdgcn_exp2f((mrow[r] - mnew[r]) * csc);
            mrow[r]  = mnew[r];
            rs[r]    = 0.f;
        }
        #pragma unroll
        for (int jt = 0; jt < 4; ++jt) {
            #pragma unroll
            for (int r = 0; r < 4; ++r) {
                float p = __builtin_amdgcn_exp2f((s[jt][r] - mnew[r]) * csc);
                rs[r] += p;
                // XOR swizzle: physical col = col ^ ((row>>2)<<4); row>>2 == quad
                Ps[w][(quad * 4 + r) * 64 + ((jt * 16 + l15) ^ (quad << 4))] = (short)f2bf(p);
            }
        }
        #pragma unroll
        for (int r = 0; r < 4; ++r) {
            float t = rs[r];
            t += __shfl_xor(t, 1);
            t += __shfl_xor(t, 2);
            t += __shfl_xor(t, 4);
            t += __shfl_xor(t, 8);
            lrow[r] = lrow[r] * alpha[r] + t;
            #pragma unroll
            for (int dt = 0; dt < 4; ++dt) o[dt][r] *= alpha[r];
        }
        __syncthreads();   // Ps visible for A-layout re-read

        // O += P @ V   (A-frag row = l15 -> unswizzle with (l15>>2)<<4)
        #pragma unroll
        for (int f = 0; f < 2; ++f) {
            bf16x8 pf = *(const bf16x8*)&Ps[w][l15 * 64 + ((f * 32 + quad * 8) ^ ((l15 >> 2) << 4))];
            #pragma unroll
            for (int dt = 0; dt < 4; ++dt) {
                bf16x8 vf = *(const bf16x8*)&Vs[(dt * 16 + l15) * 64 + f * 32 + quad * 8];
                o[dt] = __builtin_amdgcn_mfma_f32_16x16x32_bf16(pf, vf, o[dt], 0, 0, 0);
            }
        }
    }

    #pragma unroll
    for (int r = 0; r < 4; ++r) {
        int row = q0 + w * 16 + quad * 4 + r;
        float inv = 1.f / lrow[r];
        #pragma unroll
        for (int dt = 0; dt < 4; ++dt) {
            int col = h * DH + dt * 16 + l15;
            Ow[(size_t)row * D_MODEL + col] = (short)f2bf(o[dt][r] * inv);
        }
    }
}

extern "C" void kernel_launch(void* const* d_in, const int* in_sizes, int n_in,
                              void* d_out, int out_size, void* d_ws, size_t ws_size,
                              hipStream_t stream) {
    // Reference dtypes: ALL inputs float32; output float32.
    const float* Q   = (const float*)d_in[0];
    const float* K   = (const float*)d_in[1];
    const float* V   = (const float*)d_in[2];
    const float* w_q = (const float*)d_in[3];
    const float* b_q = (const float*)d_in[4];
    const float* w_k = (const float*)d_in[5];
    const float* b_k = (const float*)d_in[6];
    const float* w_v = (const float*)d_in[7];
    const float* b_v = (const float*)d_in[8];
    const float* w_o = (const float*)d_in[9];
    const float* b_o = (const float*)d_in[10];
    float* out = (float*)d_out;

    const int L = in_sizes[0] / D_MODEL;   // 4096
    const size_t mat = (size_t)L * D_MODEL;

    // bf16 intermediates: q,k,a in d_ws (24 MB); projected V borrows the
    // upper 8 MB of the 16 MB fp32 d_out (dead before out_proj overwrites;
    // stream-ordered, every byte of d_out rewritten each call).
    ushort* q_ws = (ushort*)d_ws;
    ushort* k_ws = q_ws + mat;
    ushort* a_ws = k_ws + mat;
    ushort* v_ws = (ushort*)d_out + mat;   // bytes [8MB,16MB) of d_out

    dim3 gqkv(D_MODEL / 128, L / 128, 3);
    qkv_proj_kernel<<<gqkv, dim3(256), 0, stream>>>(Q, K, V, w_q, b_q, w_k, b_k, w_v, b_v,
                                                    q_ws, k_ws, v_ws, L);
    dim3 gattn(L / 128, NHEAD);
    attn_kernel<<<gattn, dim3(512), 0, stream>>>(q_ws, k_ws, v_ws, a_ws, L);
    dim3 gout(D_MODEL / 128, L / 128);
    out_proj_kernel<<<gout, dim3(256), 0, stream>>>(a_ws, w_o, b_o, out, L);
}

// Round 6
// 429.726 us; speedup vs baseline: 1.4339x; 1.1414x over previous
//
#include <hip/hip_runtime.h>
#include <hip/hip_bf16.h>
#include <stdint.h>

#define D_MODEL 1024
#define NHEAD   16
#define DH      64

typedef __attribute__((ext_vector_type(8))) short bf16x8;
typedef __attribute__((ext_vector_type(4))) float f32x4;

__device__ __forceinline__ ushort f2bf(float f) {
    __hip_bfloat16 h = __float2bfloat16(f);
    return *reinterpret_cast<ushort*>(&h);
}

// Load 8 contiguous elements as bf16x8; fp32 source converts in-register.
__device__ __forceinline__ bf16x8 load8(const float* p) {
    const float4 a = *(const float4*)p;
    const float4 b = *(const float4*)(p + 4);
    bf16x8 r;
    r[0] = (short)f2bf(a.x); r[1] = (short)f2bf(a.y);
    r[2] = (short)f2bf(a.z); r[3] = (short)f2bf(a.w);
    r[4] = (short)f2bf(b.x); r[5] = (short)f2bf(b.y);
    r[6] = (short)f2bf(b.z); r[7] = (short)f2bf(b.w);
    return r;
}
__device__ __forceinline__ bf16x8 load8(const ushort* p) {
    return *(const bf16x8*)p;
}

__device__ __forceinline__ void storeC(float*  C, size_t i, float v) { C[i] = v; }
__device__ __forceinline__ void storeC(ushort* C, size_t i, float v) { C[i] = (short)f2bf(v); }

// C = X (MxK) @ W^T (W is NxK) + bias, C row-major (MxN). bf16 MFMA compute.
template<typename TX, typename TW, typename TOUT>
__device__ __forceinline__ void gemm_core(
    const TX* __restrict__ X,
    const TW* __restrict__ W,
    const float* __restrict__ Bias,
    TOUT* __restrict__ C,
    int M, int N, int K,
    short* As, short* Bs)
{
    const int tid  = threadIdx.x;
    const int w    = tid >> 6;
    const int lane = tid & 63;
    const int quad = lane >> 4;
    const int l15  = lane & 15;
    const int wr   = w >> 1, wc = w & 1;
    const int m0 = blockIdx.y * 128;
    const int n0 = blockIdx.x * 128;

    f32x4 acc[4][4] = {};

    for (int k0 = 0; k0 < K; k0 += 32) {
        __syncthreads();   // WAR on LDS tiles
        #pragma unroll
        for (int c = 0; c < 2; ++c) {
            int idx = c * 256 + tid;        // 0..511
            int row = idx >> 2;             // 0..127
            int col = (idx & 3) * 8;        // 0,8,16,24
            *(bf16x8*)&As[row * 32 + col] = load8(X + (size_t)(m0 + row) * K + k0 + col);
            *(bf16x8*)&Bs[row * 32 + col] = load8(W + (size_t)(n0 + row) * K + k0 + col);
        }
        __syncthreads();

        bf16x8 af[4], bfr[4];
        #pragma unroll
        for (int i = 0; i < 4; ++i)
            af[i] = *(const bf16x8*)&As[(wr * 64 + i * 16 + l15) * 32 + quad * 8];
        #pragma unroll
        for (int j = 0; j < 4; ++j)
            bfr[j] = *(const bf16x8*)&Bs[(wc * 64 + j * 16 + l15) * 32 + quad * 8];
        #pragma unroll
        for (int i = 0; i < 4; ++i)
            #pragma unroll
            for (int j = 0; j < 4; ++j)
                acc[i][j] = __builtin_amdgcn_mfma_f32_16x16x32_bf16(af[i], bfr[j], acc[i][j], 0, 0, 0);
    }

    float bias[4];
    #pragma unroll
    for (int j = 0; j < 4; ++j)
        bias[j] = Bias[n0 + wc * 64 + j * 16 + l15];

    #pragma unroll
    for (int i = 0; i < 4; ++i) {
        int row = m0 + wr * 64 + i * 16 + quad * 4;
        #pragma unroll
        for (int j = 0; j < 4; ++j) {
            int col = n0 + wc * 64 + j * 16 + l15;
            #pragma unroll
            for (int r = 0; r < 4; ++r)
                storeC(C, (size_t)(row + r) * N + col, acc[i][j][r] + bias[j]);
        }
    }
}

__global__ __launch_bounds__(256) void qkv_proj_kernel(
    const float* __restrict__ Qin, const float* __restrict__ Kin,
    const float* __restrict__ Vin,
    const float* __restrict__ Wq, const float* __restrict__ Bq,
    const float* __restrict__ Wk, const float* __restrict__ Bk,
    const float* __restrict__ Wv, const float* __restrict__ Bv,
    ushort* qo, ushort* ko, ushort* vo, int L)
{
    __shared__ short As[4096];
    __shared__ short Bs[4096];
    const int z = blockIdx.z;
    const float *X, *W, *B; ushort* C;
    if (z == 0)      { X = Qin; W = Wq; B = Bq; C = qo; }
    else if (z == 1) { X = Kin; W = Wk; B = Bk; C = ko; }
    else             { X = Vin; W = Wv; B = Bv; C = vo; }
    gemm_core<float, float, ushort>(X, W, B, C, L, D_MODEL, D_MODEL, As, Bs);
}

__global__ __launch_bounds__(256) void out_proj_kernel(
    const ushort* __restrict__ Xa, const float* __restrict__ Wo,
    const float* __restrict__ Bo, float* out, int L)
{
    __shared__ short As[4096];
    __shared__ short Bs[4096];
    gemm_core<ushort, float, float>(Xa, Wo, Bo, out, L, D_MODEL, D_MODEL, As, Bs);
}

// Flash attention. Block = (128 Q rows, head), 512 threads (8 waves x 16 q-rows).
// Ks/Vs use XOR bank swizzle: physical 8-short group = col8 ^ (row & 7).
__global__ __launch_bounds__(512) void attn_kernel(
    const ushort* __restrict__ Qw,
    const ushort* __restrict__ Kw,
    const ushort* __restrict__ Vw,
    ushort* __restrict__ Ow, int L)
{
    __shared__ short Ks[64 * 64];       // [key][dh]   swizzled
    __shared__ short Vs[64 * 64];       // [dh][key]   swizzled
    __shared__ short Ps[8][16 * 64];    // per-wave P tile, XOR-swizzled columns

    const int tid  = threadIdx.x;
    const int w    = tid >> 6;          // 0..7
    const int lane = tid & 63;
    const int quad = lane >> 4;
    const int l15  = lane & 15;
    const int h    = blockIdx.y;
    const int q0   = blockIdx.x * 128;

    // Q A-fragments held in registers for the whole block
    const ushort* qp = Qw + (size_t)(q0 + w * 16 + l15) * D_MODEL + h * DH + quad * 8;
    bf16x8 qf0 = *(const bf16x8*)(qp);
    bf16x8 qf1 = *(const bf16x8*)(qp + 32);

    // staging coordinates
    const int kkey = tid >> 3;          // K: 8 lanes per row -> coalesced global read
    const int kc8  = tid & 7;           // col8 within row
    const int vkey = lane;              // V: lane = key
    const int vdh  = w * 8;

    // precomputed swizzled fragment offsets (read side)
    // Ks read: row = jt*16 + l15, col8 = quad (f0) / quad+4 (f1)
    const int krswz0 = ((quad    ) ^ (l15 & 7)) * 8;
    const int krswz1 = ((quad + 4) ^ (l15 & 7)) * 8;

    f32x4 o[4] = {};
    float mrow[4] = {-3e38f, -3e38f, -3e38f, -3e38f};
    float lrow[4] = {0.f, 0.f, 0.f, 0.f};
    const float csc = 0.125f * 1.44269504088896f;   // log2(e)/sqrt(Dh)

    for (int key0 = 0; key0 < L; key0 += 64) {
        __syncthreads();   // WAR on Ks/Vs
        // K stage: write 16B at swizzled group (kc8 ^ (kkey&7))
        *(bf16x8*)&Ks[kkey * 64 + ((kc8 ^ (kkey & 7)) * 8)] =
            *(const bf16x8*)(Kw + (size_t)(key0 + kkey) * D_MODEL + h * DH + kc8 * 8);
        // V stage (transpose): row = vdh+i, col = vkey; (vdh+i)&7 == i
        bf16x8 vv = *(const bf16x8*)(Vw + (size_t)(key0 + vkey) * D_MODEL + h * DH + vdh);
        #pragma unroll
        for (int i = 0; i < 8; ++i)
            Vs[(vdh + i) * 64 + (((vkey >> 3) ^ i) * 8) + (vkey & 7)] = vv[i];
        __syncthreads();

        // S = Q K^T (raw; scale folded into exp2 constant)
        f32x4 s[4];
        #pragma unroll
        for (int jt = 0; jt < 4; ++jt) {
            const int kr = (jt * 16 + l15) * 64;
            bf16x8 kf0 = *(const bf16x8*)&Ks[kr + krswz0];
            bf16x8 kf1 = *(const bf16x8*)&Ks[kr + krswz1];
            f32x4 z = {};
            z = __builtin_amdgcn_mfma_f32_16x16x32_bf16(qf0, kf0, z, 0, 0, 0);
            z = __builtin_amdgcn_mfma_f32_16x16x32_bf16(qf1, kf1, z, 0, 0, 0);
            s[jt] = z;
        }

        // online softmax (rows = quad*4 + r within wave's 16-row tile)
        float mnew[4], alpha[4], rs[4];
        #pragma unroll
        for (int r = 0; r < 4; ++r) {
            float mx = fmaxf(fmaxf(s[0][r], s[1][r]), fmaxf(s[2][r], s[3][r]));
            mx = fmaxf(mx, __shfl_xor(mx, 1));
            mx = fmaxf(mx, __shfl_xor(mx, 2));
            mx = fmaxf(mx, __shfl_xor(mx, 4));
            mx = fmaxf(mx, __shfl_xor(mx, 8));
            mnew[r]  = fmaxf(mrow[r], mx);
            alpha[r] = __builtin_amdgcn_exp2f((mrow[r] - mnew[r]) * csc);
            mrow[r]  = mnew[r];
            rs[r]    = 0.f;
        }
        #pragma unroll
        for (int jt = 0; jt < 4; ++jt) {
            #pragma unroll
            for (int r = 0; r < 4; ++r) {
                float p = __builtin_amdgcn_exp2f((s[jt][r] - mnew[r]) * csc);
                rs[r] += p;
                // XOR swizzle: physical col = col ^ (quad<<4)
                Ps[w][(quad * 4 + r) * 64 + ((jt * 16 + l15) ^ (quad << 4))] = (short)f2bf(p);
            }
        }
        #pragma unroll
        for (int r = 0; r < 4; ++r) {
            float t = rs[r];
            t += __shfl_xor(t, 1);
            t += __shfl_xor(t, 2);
            t += __shfl_xor(t, 4);
            t += __shfl_xor(t, 8);
            lrow[r] = lrow[r] * alpha[r] + t;
            #pragma unroll
            for (int dt = 0; dt < 4; ++dt) o[dt][r] *= alpha[r];
        }
        // NO __syncthreads here: Ps[w] is wave-private; per-wave DS ops are
        // processed in program order, so the b128 reads below see the writes.

        // O += P @ V   (A-frag row = l15 -> unswizzle with (l15>>2)<<4)
        #pragma unroll
        for (int f = 0; f < 2; ++f) {
            bf16x8 pf = *(const bf16x8*)&Ps[w][l15 * 64 + ((f * 32 + quad * 8) ^ ((l15 >> 2) << 4))];
            #pragma unroll
            for (int dt = 0; dt < 4; ++dt) {
                const int vr = (dt * 16 + l15) * 64;
                bf16x8 vf = *(const bf16x8*)&Vs[vr + (((f * 4 + quad) ^ (l15 & 7)) * 8)];
                o[dt] = __builtin_amdgcn_mfma_f32_16x16x32_bf16(pf, vf, o[dt], 0, 0, 0);
            }
        }
    }

    #pragma unroll
    for (int r = 0; r < 4; ++r) {
        int row = q0 + w * 16 + quad * 4 + r;
        float inv = 1.f / lrow[r];
        #pragma unroll
        for (int dt = 0; dt < 4; ++dt) {
            int col = h * DH + dt * 16 + l15;
            Ow[(size_t)row * D_MODEL + col] = (short)f2bf(o[dt][r] * inv);
        }
    }
}

extern "C" void kernel_launch(void* const* d_in, const int* in_sizes, int n_in,
                              void* d_out, int out_size, void* d_ws, size_t ws_size,
                              hipStream_t stream) {
    // Reference dtypes: ALL inputs float32; output float32.
    const float* Q   = (const float*)d_in[0];
    const float* K   = (const float*)d_in[1];
    const float* V   = (const float*)d_in[2];
    const float* w_q = (const float*)d_in[3];
    const float* b_q = (const float*)d_in[4];
    const float* w_k = (const float*)d_in[5];
    const float* b_k = (const float*)d_in[6];
    const float* w_v = (const float*)d_in[7];
    const float* b_v = (const float*)d_in[8];
    const float* w_o = (const float*)d_in[9];
    const float* b_o = (const float*)d_in[10];
    float* out = (float*)d_out;

    const int L = in_sizes[0] / D_MODEL;   // 4096
    const size_t mat = (size_t)L * D_MODEL;

    // bf16 intermediates: q,k,a in d_ws (24 MB); projected V borrows the
    // upper 8 MB of the 16 MB fp32 d_out (dead before out_proj overwrites;
    // stream-ordered, every byte of d_out rewritten each call).
    ushort* q_ws = (ushort*)d_ws;
    ushort* k_ws = q_ws + mat;
    ushort* a_ws = k_ws + mat;
    ushort* v_ws = (ushort*)d_out + mat;   // bytes [8MB,16MB) of d_out

    dim3 gqkv(D_MODEL / 128, L / 128, 3);
    qkv_proj_kernel<<<gqkv, dim3(256), 0, stream>>>(Q, K, V, w_q, b_q, w_k, b_k, w_v, b_v,
                                                    q_ws, k_ws, v_ws, L);
    dim3 gattn(L / 128, NHEAD);
    attn_kernel<<<gattn, dim3(512), 0, stream>>>(q_ws, k_ws, v_ws, a_ws, L);
    dim3 gout(D_MODEL / 128, L / 128);
    out_proj_kernel<<<gout, dim3(256), 0, stream>>>(a_ws, w_o, b_o, out, L);
}

// Round 7
// 337.496 us; speedup vs baseline: 1.8257x; 1.2733x over previous
//
#include <hip/hip_runtime.h>
#include <hip/hip_bf16.h>
#include <stdint.h>

#define D_MODEL 1024
#define NHEAD   16
#define DH      64

typedef __attribute__((ext_vector_type(8))) short bf16x8;
typedef __attribute__((ext_vector_type(4))) float f32x4;

__device__ __forceinline__ ushort f2bf(float f) {
    __hip_bfloat16 h = __float2bfloat16(f);
    return *reinterpret_cast<ushort*>(&h);
}

// Load 8 contiguous elements as bf16x8; fp32 source converts in-register.
__device__ __forceinline__ bf16x8 load8(const float* p) {
    const float4 a = *(const float4*)p;
    const float4 b = *(const float4*)(p + 4);
    bf16x8 r;
    r[0] = (short)f2bf(a.x); r[1] = (short)f2bf(a.y);
    r[2] = (short)f2bf(a.z); r[3] = (short)f2bf(a.w);
    r[4] = (short)f2bf(b.x); r[5] = (short)f2bf(b.y);
    r[6] = (short)f2bf(b.z); r[7] = (short)f2bf(b.w);
    return r;
}
__device__ __forceinline__ bf16x8 load8(const ushort* p) {
    return *(const bf16x8*)p;
}

__device__ __forceinline__ void storeC(float*  C, size_t i, float v) { C[i] = v; }
__device__ __forceinline__ void storeC(ushort* C, size_t i, float v) { C[i] = (short)f2bf(v); }

// C = X (MxK) @ W^T (W is NxK) + bias, C row-major (MxN). bf16 MFMA compute.
template<typename TX, typename TW, typename TOUT>
__device__ __forceinline__ void gemm_core(
    const TX* __restrict__ X,
    const TW* __restrict__ W,
    const float* __restrict__ Bias,
    TOUT* __restrict__ C,
    int M, int N, int K,
    short* As, short* Bs)
{
    const int tid  = threadIdx.x;
    const int w    = tid >> 6;
    const int lane = tid & 63;
    const int quad = lane >> 4;
    const int l15  = lane & 15;
    const int wr   = w >> 1, wc = w & 1;
    const int m0 = blockIdx.y * 128;
    const int n0 = blockIdx.x * 128;

    f32x4 acc[4][4] = {};

    for (int k0 = 0; k0 < K; k0 += 32) {
        __syncthreads();   // WAR on LDS tiles
        #pragma unroll
        for (int c = 0; c < 2; ++c) {
            int idx = c * 256 + tid;        // 0..511
            int row = idx >> 2;             // 0..127
            int col = (idx & 3) * 8;        // 0,8,16,24
            *(bf16x8*)&As[row * 32 + col] = load8(X + (size_t)(m0 + row) * K + k0 + col);
            *(bf16x8*)&Bs[row * 32 + col] = load8(W + (size_t)(n0 + row) * K + k0 + col);
        }
        __syncthreads();

        bf16x8 af[4], bfr[4];
        #pragma unroll
        for (int i = 0; i < 4; ++i)
            af[i] = *(const bf16x8*)&As[(wr * 64 + i * 16 + l15) * 32 + quad * 8];
        #pragma unroll
        for (int j = 0; j < 4; ++j)
            bfr[j] = *(const bf16x8*)&Bs[(wc * 64 + j * 16 + l15) * 32 + quad * 8];
        #pragma unroll
        for (int i = 0; i < 4; ++i)
            #pragma unroll
            for (int j = 0; j < 4; ++j)
                acc[i][j] = __builtin_amdgcn_mfma_f32_16x16x32_bf16(af[i], bfr[j], acc[i][j], 0, 0, 0);
    }

    float bias[4];
    #pragma unroll
    for (int j = 0; j < 4; ++j)
        bias[j] = Bias[n0 + wc * 64 + j * 16 + l15];

    #pragma unroll
    for (int i = 0; i < 4; ++i) {
        int row = m0 + wr * 64 + i * 16 + quad * 4;
        #pragma unroll
        for (int j = 0; j < 4; ++j) {
            int col = n0 + wc * 64 + j * 16 + l15;
            #pragma unroll
            for (int r = 0; r < 4; ++r)
                storeC(C, (size_t)(row + r) * N + col, acc[i][j][r] + bias[j]);
        }
    }
}

__global__ __launch_bounds__(256) void qkv_proj_kernel(
    const float* __restrict__ Qin, const float* __restrict__ Kin,
    const float* __restrict__ Vin,
    const float* __restrict__ Wq, const float* __restrict__ Bq,
    const float* __restrict__ Wk, const float* __restrict__ Bk,
    const float* __restrict__ Wv, const float* __restrict__ Bv,
    ushort* qo, ushort* ko, ushort* vo, int L)
{
    __shared__ short As[4096];
    __shared__ short Bs[4096];
    const int z = blockIdx.z;
    const float *X, *W, *B; ushort* C;
    if (z == 0)      { X = Qin; W = Wq; B = Bq; C = qo; }
    else if (z == 1) { X = Kin; W = Wk; B = Bk; C = ko; }
    else             { X = Vin; W = Wv; B = Bv; C = vo; }
    gemm_core<float, float, ushort>(X, W, B, C, L, D_MODEL, D_MODEL, As, Bs);
}

__global__ __launch_bounds__(256) void out_proj_kernel(
    const ushort* __restrict__ Xa, const float* __restrict__ Wo,
    const float* __restrict__ Bo, float* out, int L)
{
    __shared__ short As[4096];
    __shared__ short Bs[4096];
    gemm_core<ushort, float, float>(Xa, Wo, Bo, out, L, D_MODEL, D_MODEL, As, Bs);
}

// Flash attention, transposed-score form: St = K·Q^T so each lane owns all
// scores of one query (l15). Block = (128 Q rows, head), 512 threads.
// Ks/Vs XOR-swizzled (group8 ^ (row&7)); Ps [query][key] swizzled at group8.
__global__ __launch_bounds__(512) void attn_kernel(
    const ushort* __restrict__ Qw,
    const ushort* __restrict__ Kw,
    const ushort* __restrict__ Vw,
    ushort* __restrict__ Ow, int L)
{
    __shared__ short Ks[64 * 64];       // [key][dh]   swizzled
    __shared__ short Vs[64 * 64];       // [dh][key]   swizzled
    __shared__ short Ps[8][16 * 64];    // per-wave P [query][key], swizzled

    const int tid  = threadIdx.x;
    const int w    = tid >> 6;          // 0..7
    const int lane = tid & 63;
    const int quad = lane >> 4;
    const int l15  = lane & 15;
    const int h    = blockIdx.y;
    const int q0   = blockIdx.x * 128;

    // Q fragments (B-operand now; same [l15][quad*8+j] lane mapping)
    const ushort* qp = Qw + (size_t)(q0 + w * 16 + l15) * D_MODEL + h * DH + quad * 8;
    bf16x8 qf0 = *(const bf16x8*)(qp);
    bf16x8 qf1 = *(const bf16x8*)(qp + 32);

    // staging coordinates
    const int kkey = tid >> 3;          // K: 8 lanes per row -> coalesced global read
    const int kc8  = tid & 7;           // col8 within row
    const int vkey = lane;              // V: lane = key
    const int vdh  = w * 8;

    // swizzled fragment offsets: group8 index ^ (row&7)
    const int krswz0 = ((quad    ) ^ (l15 & 7)) * 8;
    const int krswz1 = ((quad + 4) ^ (l15 & 7)) * 8;

    f32x4 o[4] = {};
    float m_run = -3e38f, l_run = 0.f;
    const float csc = 0.125f * 1.44269504088896f;   // log2(e)/sqrt(Dh)

    for (int key0 = 0; key0 < L; key0 += 64) {
        __syncthreads();   // WAR on Ks/Vs
        *(bf16x8*)&Ks[kkey * 64 + ((kc8 ^ (kkey & 7)) * 8)] =
            *(const bf16x8*)(Kw + (size_t)(key0 + kkey) * D_MODEL + h * DH + kc8 * 8);
        bf16x8 vv = *(const bf16x8*)(Vw + (size_t)(key0 + vkey) * D_MODEL + h * DH + vdh);
        #pragma unroll
        for (int i = 0; i < 8; ++i)
            Vs[(vdh + i) * 64 + (((vkey >> 3) ^ i) * 8) + (vkey & 7)] = vv[i];
        __syncthreads();

        // St = K·Q^T: st[kt][r] = S[key = kt*16+quad*4+r][query = l15]
        f32x4 st[4];
        #pragma unroll
        for (int kt = 0; kt < 4; ++kt) {
            const int kr = (kt * 16 + l15) * 64;
            bf16x8 kf0 = *(const bf16x8*)&Ks[kr + krswz0];
            bf16x8 kf1 = *(const bf16x8*)&Ks[kr + krswz1];
            f32x4 z = {};
            z = __builtin_amdgcn_mfma_f32_16x16x32_bf16(kf0, qf0, z, 0, 0, 0);
            z = __builtin_amdgcn_mfma_f32_16x16x32_bf16(kf1, qf1, z, 0, 0, 0);
            st[kt] = z;
        }

        // per-lane max over this lane's 16 keys, then across quads
        float mx = st[0][0];
        #pragma unroll
        for (int kt = 0; kt < 4; ++kt)
            #pragma unroll
            for (int r = 0; r < 4; ++r)
                mx = fmaxf(mx, st[kt][r]);
        mx = fmaxf(mx, __shfl_xor(mx, 16));
        mx = fmaxf(mx, __shfl_xor(mx, 32));
        const float mnew  = fmaxf(m_run, mx);
        const float alpha = __builtin_amdgcn_exp2f((m_run - mnew) * csc);
        m_run = mnew;

        // P = exp2((St-m)*csc); pack 4 consecutive keys -> one b64 write
        float rs = 0.f;
        #pragma unroll
        for (int kt = 0; kt < 4; ++kt) {
            float p0 = __builtin_amdgcn_exp2f((st[kt][0] - mnew) * csc);
            float p1 = __builtin_amdgcn_exp2f((st[kt][1] - mnew) * csc);
            float p2 = __builtin_amdgcn_exp2f((st[kt][2] - mnew) * csc);
            float p3 = __builtin_amdgcn_exp2f((st[kt][3] - mnew) * csc);
            rs += (p0 + p1) + (p2 + p3);
            uint2 pk;
            pk.x = (uint32_t)f2bf(p0) | ((uint32_t)f2bf(p1) << 16);
            pk.y = (uint32_t)f2bf(p2) | ((uint32_t)f2bf(p3) << 16);
            const int G = kt * 2 + (quad >> 1);          // key group-of-8
            *(uint2*)&Ps[w][l15 * 64 + ((G ^ (l15 & 7)) * 8) + (quad & 1) * 4] = pk;
        }
        rs += __shfl_xor(rs, 16);
        rs += __shfl_xor(rs, 32);
        l_run = l_run * alpha + rs;

        // redistribute alpha from query-lane (l15=q) to O-row positions
        float a[4];
        #pragma unroll
        for (int r = 0; r < 4; ++r)
            a[r] = __shfl(alpha, (lane & 48) | (quad * 4 + r));
        #pragma unroll
        for (int dt = 0; dt < 4; ++dt)
            #pragma unroll
            for (int r = 0; r < 4; ++r)
                o[dt][r] *= a[r];
        // no barrier: Ps[w] is wave-private, per-wave DS ops are in-order

        // O += P·V  (A = Ps[query][key], B = Vs[dh][key])
        #pragma unroll
        for (int f = 0; f < 2; ++f) {
            bf16x8 pf = *(const bf16x8*)&Ps[w][l15 * 64 + (((f * 4 + quad) ^ (l15 & 7)) * 8)];
            #pragma unroll
            for (int dt = 0; dt < 4; ++dt) {
                bf16x8 vf = *(const bf16x8*)&Vs[(dt * 16 + l15) * 64 + (((f * 4 + quad) ^ (l15 & 7)) * 8)];
                o[dt] = __builtin_amdgcn_mfma_f32_16x16x32_bf16(pf, vf, o[dt], 0, 0, 0);
            }
        }
    }

    // epilogue: per-query 1/l, redistributed like alpha
    const float inv = 1.f / l_run;
    #pragma unroll
    for (int r = 0; r < 4; ++r) {
        const float linv = __shfl(inv, (lane & 48) | (quad * 4 + r));
        const int row = q0 + w * 16 + quad * 4 + r;
        #pragma unroll
        for (int dt = 0; dt < 4; ++dt) {
            int col = h * DH + dt * 16 + l15;
            Ow[(size_t)row * D_MODEL + col] = (short)f2bf(o[dt][r] * linv);
        }
    }
}

extern "C" void kernel_launch(void* const* d_in, const int* in_sizes, int n_in,
                              void* d_out, int out_size, void* d_ws, size_t ws_size,
                              hipStream_t stream) {
    // Reference dtypes: ALL inputs float32; output float32.
    const float* Q   = (const float*)d_in[0];
    const float* K   = (const float*)d_in[1];
    const float* V   = (const float*)d_in[2];
    const float* w_q = (const float*)d_in[3];
    const float* b_q = (const float*)d_in[4];
    const float* w_k = (const float*)d_in[5];
    const float* b_k = (const float*)d_in[6];
    const float* w_v = (const float*)d_in[7];
    const float* b_v = (const float*)d_in[8];
    const float* w_o = (const float*)d_in[9];
    const float* b_o = (const float*)d_in[10];
    float* out = (float*)d_out;

    const int L = in_sizes[0] / D_MODEL;   // 4096
    const size_t mat = (size_t)L * D_MODEL;

    // bf16 intermediates: q,k,a in d_ws (24 MB); projected V borrows the
    // upper 8 MB of the 16 MB fp32 d_out (dead before out_proj overwrites;
    // stream-ordered, every byte of d_out rewritten each call).
    ushort* q_ws = (ushort*)d_ws;
    ushort* k_ws = q_ws + mat;
    ushort* a_ws = k_ws + mat;
    ushort* v_ws = (ushort*)d_out + mat;   // bytes [8MB,16MB) of d_out

    dim3 gqkv(D_MODEL / 128, L / 128, 3);
    qkv_proj_kernel<<<gqkv, dim3(256), 0, stream>>>(Q, K, V, w_q, b_q, w_k, b_k, w_v, b_v,
                                                    q_ws, k_ws, v_ws, L);
    dim3 gattn(L / 128, NHEAD);
    attn_kernel<<<gattn, dim3(512), 0, stream>>>(q_ws, k_ws, v_ws, a_ws, L);
    dim3 gout(D_MODEL / 128, L / 128);
    out_proj_kernel<<<gout, dim3(256), 0, stream>>>(a_ws, w_o, b_o, out, L);
}

// Round 8
// 327.653 us; speedup vs baseline: 1.8806x; 1.0300x over previous
//
#include <hip/hip_runtime.h>
#include <hip/hip_bf16.h>
#include <stdint.h>

#define D_MODEL 1024
#define NHEAD   16
#define DH      64

typedef __attribute__((ext_vector_type(8))) short bf16x8;
typedef __attribute__((ext_vector_type(4))) float f32x4;

__device__ __forceinline__ ushort f2bf(float f) {
    __hip_bfloat16 h = __float2bfloat16(f);
    return *reinterpret_cast<ushort*>(&h);
}

__device__ __forceinline__ void gload_lds16(const void* g, void* l) {
    __builtin_amdgcn_global_load_lds(
        (const __attribute__((address_space(1))) void*)g,
        (__attribute__((address_space(3))) void*)l, 16, 0, 0);
}

// Load 8 contiguous fp32, convert to bf16x8 in-register.
__device__ __forceinline__ bf16x8 load8f(const float* p) {
    const float4 a = *(const float4*)p;
    const float4 b = *(const float4*)(p + 4);
    bf16x8 r;
    r[0] = (short)f2bf(a.x); r[1] = (short)f2bf(a.y);
    r[2] = (short)f2bf(a.z); r[3] = (short)f2bf(a.w);
    r[4] = (short)f2bf(b.x); r[5] = (short)f2bf(b.y);
    r[6] = (short)f2bf(b.z); r[7] = (short)f2bf(b.w);
    return r;
}

// fp32 -> bf16 weight conversion: 4 matrices of 1M elements each.
__global__ __launch_bounds__(256) void cvt_w_kernel(
    const float* __restrict__ w0, const float* __restrict__ w1,
    const float* __restrict__ w2, const float* __restrict__ w3,
    ushort* __restrict__ out)
{
    const int g = blockIdx.x * 256 + threadIdx.x;   // group of 8 elems
    const int m = g >> 17;                          // 131072 groups / matrix
    const int off = (g & 131071) * 8;
    const float* src = (m == 0) ? w0 : (m == 1) ? w1 : (m == 2) ? w2 : w3;
    *(bf16x8*)(out + (size_t)m * 1048576 + off) = load8f(src + off);
}

// ---- shared GEMM epilogue helpers ----
__device__ __forceinline__ void storeC(float*  C, size_t i, float v) { C[i] = v; }
__device__ __forceinline__ void storeC(ushort* C, size_t i, float v) { C[i] = (short)f2bf(v); }

// C = X(MxK) @ Wb^T (Wb NxK bf16) + bias. A_F32: X is fp32 (explicit staging);
// else X is bf16 ushort (global_load_lds). B always via global_load_lds.
template<bool A_F32, typename TX, typename TOUT>
__device__ __forceinline__ void gemm_core(
    const TX* __restrict__ X,
    const ushort* __restrict__ Wb,
    const float* __restrict__ Bias,
    TOUT* __restrict__ C,
    int M, int N, int K,
    short* As, short* Bs)
{
    const int tid  = threadIdx.x;
    const int w    = tid >> 6;
    const int lane = tid & 63;
    const int quad = lane >> 4;
    const int l15  = lane & 15;
    const int wr   = w >> 1, wc = w & 1;
    const int m0 = blockIdx.y * 128;
    const int n0 = blockIdx.x * 128;

    f32x4 acc[4][4] = {};

    for (int k0 = 0; k0 < K; k0 += 32) {
        __syncthreads();   // WAR on LDS tiles
        // B-tile: 8 chunks of 1 KB, 2 per wave, DMA direct to LDS.
        // LDS dest = base + lane*16 == Bs[(chunk*16 + lane>>2)*32 + (lane&3)*8]
        #pragma unroll
        for (int c = 0; c < 2; ++c) {
            int chunk = w * 2 + c;
            int row   = chunk * 16 + (lane >> 2);
            gload_lds16(Wb + (size_t)(n0 + row) * K + k0 + (lane & 3) * 8,
                        &Bs[chunk * 512]);
        }
        // A-tile
        if (A_F32) {
            #pragma unroll
            for (int c = 0; c < 2; ++c) {
                int idx = c * 256 + tid;
                int row = idx >> 2;
                int col = (idx & 3) * 8;
                *(bf16x8*)&As[row * 32 + col] =
                    load8f((const float*)X + (size_t)(m0 + row) * K + k0 + col);
            }
        } else {
            #pragma unroll
            for (int c = 0; c < 2; ++c) {
                int chunk = w * 2 + c;
                int row   = chunk * 16 + (lane >> 2);
                gload_lds16((const ushort*)X + (size_t)(m0 + row) * K + k0 + (lane & 3) * 8,
                            &As[chunk * 512]);
            }
        }
        __syncthreads();   // drains vmcnt (DMA) + lgkmcnt before use

        bf16x8 af[4], bfr[4];
        #pragma unroll
        for (int i = 0; i < 4; ++i)
            af[i] = *(const bf16x8*)&As[(wr * 64 + i * 16 + l15) * 32 + quad * 8];
        #pragma unroll
        for (int j = 0; j < 4; ++j)
            bfr[j] = *(const bf16x8*)&Bs[(wc * 64 + j * 16 + l15) * 32 + quad * 8];
        #pragma unroll
        for (int i = 0; i < 4; ++i)
            #pragma unroll
            for (int j = 0; j < 4; ++j)
                acc[i][j] = __builtin_amdgcn_mfma_f32_16x16x32_bf16(af[i], bfr[j], acc[i][j], 0, 0, 0);
    }

    float bias[4];
    #pragma unroll
    for (int j = 0; j < 4; ++j)
        bias[j] = Bias[n0 + wc * 64 + j * 16 + l15];

    #pragma unroll
    for (int i = 0; i < 4; ++i) {
        int row = m0 + wr * 64 + i * 16 + quad * 4;
        #pragma unroll
        for (int j = 0; j < 4; ++j) {
            int col = n0 + wc * 64 + j * 16 + l15;
            #pragma unroll
            for (int r = 0; r < 4; ++r)
                storeC(C, (size_t)(row + r) * N + col, acc[i][j][r] + bias[j]);
        }
    }
}

__global__ __launch_bounds__(256) void qkv_proj_kernel(
    const float* __restrict__ Qin, const float* __restrict__ Kin,
    const float* __restrict__ Vin,
    const ushort* __restrict__ Wb,
    const float* __restrict__ Bq, const float* __restrict__ Bk,
    const float* __restrict__ Bv,
    ushort* qo, ushort* ko, ushort* vo, int L)
{
    __shared__ short As[4096];
    __shared__ short Bs[4096];
    const int z = blockIdx.z;
    const float *X, *B; ushort* C;
    if (z == 0)      { X = Qin; B = Bq; C = qo; }
    else if (z == 1) { X = Kin; B = Bk; C = ko; }
    else             { X = Vin; B = Bv; C = vo; }
    gemm_core<true, float, ushort>(X, Wb + (size_t)z * 1048576, B, C,
                                   L, D_MODEL, D_MODEL, As, Bs);
}

__global__ __launch_bounds__(256) void out_proj_kernel(
    const ushort* __restrict__ Xa, const ushort* __restrict__ Wb,
    const float* __restrict__ Bo, float* out, int L)
{
    __shared__ short As[4096];
    __shared__ short Bs[4096];
    gemm_core<false, ushort, float>(Xa, Wb + (size_t)3 * 1048576, Bo, out,
                                    L, D_MODEL, D_MODEL, As, Bs);
}

// Flash attention, transposed-score form (unchanged from R7).
__global__ __launch_bounds__(512) void attn_kernel(
    const ushort* __restrict__ Qw,
    const ushort* __restrict__ Kw,
    const ushort* __restrict__ Vw,
    ushort* __restrict__ Ow, int L)
{
    __shared__ short Ks[64 * 64];
    __shared__ short Vs[64 * 64];
    __shared__ short Ps[8][16 * 64];

    const int tid  = threadIdx.x;
    const int w    = tid >> 6;
    const int lane = tid & 63;
    const int quad = lane >> 4;
    const int l15  = lane & 15;
    const int h    = blockIdx.y;
    const int q0   = blockIdx.x * 128;

    const ushort* qp = Qw + (size_t)(q0 + w * 16 + l15) * D_MODEL + h * DH + quad * 8;
    bf16x8 qf0 = *(const bf16x8*)(qp);
    bf16x8 qf1 = *(const bf16x8*)(qp + 32);

    const int kkey = tid >> 3;
    const int kc8  = tid & 7;
    const int vkey = lane;
    const int vdh  = w * 8;

    const int krswz0 = ((quad    ) ^ (l15 & 7)) * 8;
    const int krswz1 = ((quad + 4) ^ (l15 & 7)) * 8;

    f32x4 o[4] = {};
    float m_run = -3e38f, l_run = 0.f;
    const float csc = 0.125f * 1.44269504088896f;

    for (int key0 = 0; key0 < L; key0 += 64) {
        __syncthreads();
        *(bf16x8*)&Ks[kkey * 64 + ((kc8 ^ (kkey & 7)) * 8)] =
            *(const bf16x8*)(Kw + (size_t)(key0 + kkey) * D_MODEL + h * DH + kc8 * 8);
        bf16x8 vv = *(const bf16x8*)(Vw + (size_t)(key0 + vkey) * D_MODEL + h * DH + vdh);
        #pragma unroll
        for (int i = 0; i < 8; ++i)
            Vs[(vdh + i) * 64 + (((vkey >> 3) ^ i) * 8) + (vkey & 7)] = vv[i];
        __syncthreads();

        f32x4 st[4];
        #pragma unroll
        for (int kt = 0; kt < 4; ++kt) {
            const int kr = (kt * 16 + l15) * 64;
            bf16x8 kf0 = *(const bf16x8*)&Ks[kr + krswz0];
            bf16x8 kf1 = *(const bf16x8*)&Ks[kr + krswz1];
            f32x4 z = {};
            z = __builtin_amdgcn_mfma_f32_16x16x32_bf16(kf0, qf0, z, 0, 0, 0);
            z = __builtin_amdgcn_mfma_f32_16x16x32_bf16(kf1, qf1, z, 0, 0, 0);
            st[kt] = z;
        }

        float mx = st[0][0];
        #pragma unroll
        for (int kt = 0; kt < 4; ++kt)
            #pragma unroll
            for (int r = 0; r < 4; ++r)
                mx = fmaxf(mx, st[kt][r]);
        mx = fmaxf(mx, __shfl_xor(mx, 16));
        mx = fmaxf(mx, __shfl_xor(mx, 32));
        const float mnew  = fmaxf(m_run, mx);
        const float alpha = __builtin_amdgcn_exp2f((m_run - mnew) * csc);
        m_run = mnew;

        float rs = 0.f;
        #pragma unroll
        for (int kt = 0; kt < 4; ++kt) {
            float p0 = __builtin_amdgcn_exp2f((st[kt][0] - mnew) * csc);
            float p1 = __builtin_amdgcn_exp2f((st[kt][1] - mnew) * csc);
            float p2 = __builtin_amdgcn_exp2f((st[kt][2] - mnew) * csc);
            float p3 = __builtin_amdgcn_exp2f((st[kt][3] - mnew) * csc);
            rs += (p0 + p1) + (p2 + p3);
            uint2 pk;
            pk.x = (uint32_t)f2bf(p0) | ((uint32_t)f2bf(p1) << 16);
            pk.y = (uint32_t)f2bf(p2) | ((uint32_t)f2bf(p3) << 16);
            const int G = kt * 2 + (quad >> 1);
            *(uint2*)&Ps[w][l15 * 64 + ((G ^ (l15 & 7)) * 8) + (quad & 1) * 4] = pk;
        }
        rs += __shfl_xor(rs, 16);
        rs += __shfl_xor(rs, 32);
        l_run = l_run * alpha + rs;

        float a[4];
        #pragma unroll
        for (int r = 0; r < 4; ++r)
            a[r] = __shfl(alpha, (lane & 48) | (quad * 4 + r));
        #pragma unroll
        for (int dt = 0; dt < 4; ++dt)
            #pragma unroll
            for (int r = 0; r < 4; ++r)
                o[dt][r] *= a[r];

        #pragma unroll
        for (int f = 0; f < 2; ++f) {
            bf16x8 pf = *(const bf16x8*)&Ps[w][l15 * 64 + (((f * 4 + quad) ^ (l15 & 7)) * 8)];
            #pragma unroll
            for (int dt = 0; dt < 4; ++dt) {
                bf16x8 vf = *(const bf16x8*)&Vs[(dt * 16 + l15) * 64 + (((f * 4 + quad) ^ (l15 & 7)) * 8)];
                o[dt] = __builtin_amdgcn_mfma_f32_16x16x32_bf16(pf, vf, o[dt], 0, 0, 0);
            }
        }
    }

    const float inv = 1.f / l_run;
    #pragma unroll
    for (int r = 0; r < 4; ++r) {
        const float linv = __shfl(inv, (lane & 48) | (quad * 4 + r));
        const int row = q0 + w * 16 + quad * 4 + r;
        #pragma unroll
        for (int dt = 0; dt < 4; ++dt) {
            int col = h * DH + dt * 16 + l15;
            Ow[(size_t)row * D_MODEL + col] = (short)f2bf(o[dt][r] * linv);
        }
    }
}

extern "C" void kernel_launch(void* const* d_in, const int* in_sizes, int n_in,
                              void* d_out, int out_size, void* d_ws, size_t ws_size,
                              hipStream_t stream) {
    const float* Q   = (const float*)d_in[0];
    const float* K   = (const float*)d_in[1];
    const float* V   = (const float*)d_in[2];
    const float* w_q = (const float*)d_in[3];
    const float* b_q = (const float*)d_in[4];
    const float* w_k = (const float*)d_in[5];
    const float* b_k = (const float*)d_in[6];
    const float* w_v = (const float*)d_in[7];
    const float* b_v = (const float*)d_in[8];
    const float* w_o = (const float*)d_in[9];
    const float* b_o = (const float*)d_in[10];
    float* out = (float*)d_out;

    const int L = in_sizes[0] / D_MODEL;   // 4096
    const size_t mat = (size_t)L * D_MODEL;

    // Memory plan (d_ws known-safe at 24 MB; d_out = 16 MB fp32):
    //   d_ws  [0, 8MB): Wb   — 4 bf16 weight matrices (wq,wk,wv,wo)
    //   d_ws  [8,16MB): a_ws — attention output (bf16)
    //   d_ws [16,24MB): v_ws — projected V (bf16)
    //   d_out [0, 8MB): q_ws; d_out [8,16MB): k_ws — dead before out_proj
    //   writes fp32 C over all of d_out (stream-ordered; fully rewritten).
    ushort* Wb   = (ushort*)d_ws;
    ushort* a_ws = (ushort*)d_ws + 4 * 1048576;
    ushort* v_ws = a_ws + mat;
    ushort* q_ws = (ushort*)d_out;
    ushort* k_ws = q_ws + mat;

    cvt_w_kernel<<<dim3(2048), dim3(256), 0, stream>>>(w_q, w_k, w_v, w_o, Wb);

    dim3 gqkv(D_MODEL / 128, L / 128, 3);
    qkv_proj_kernel<<<gqkv, dim3(256), 0, stream>>>(Q, K, V, Wb, b_q, b_k, b_v,
                                                    q_ws, k_ws, v_ws, L);
    dim3 gattn(L / 128, NHEAD);
    attn_kernel<<<gattn, dim3(512), 0, stream>>>(q_ws, k_ws, v_ws, a_ws, L);
    dim3 gout(D_MODEL / 128, L / 128);
    out_proj_kernel<<<gout, dim3(256), 0, stream>>>(a_ws, Wb, b_o, out, L);
}